// Round 3
// baseline (580.753 us; speedup 1.0000x reference)
//
#include <hip/hip_runtime.h>
#include <math.h>

#define B_   256
#define V_   6890
#define NJ_  24
#define NB_  10
#define NP_  207
#define NJR_ 43
#define V3_  20670   // V*3
#define NK_  217     // NB + NP
#define NJ3_ 129     // NJR*3
#define JOUT_ 33024  // B*NJR*3

// ws layout (floats)
#define JSTP_OFF 0        // 8 * 792 partial Jst
#define CG_OFF   8192     // coefG: 217*256
#define A_OFF    65536    // 256*24*12 = 73728
#define JP_OFF   139264   // joint partials: 4 * 33024 = 132096

// ---------------------------------------------------------------------------
// K0: partial Jst over V-chunks.  grid (24 joints, 8 chunks).
// JstP[c][j][0..2] = sum JR*vt ; [3+k*3+d] = sum JR*sd_k
// ---------------------------------------------------------------------------
__global__ __launch_bounds__(256) void k_jst(const float* __restrict__ JR,
                                             const float* __restrict__ vtm,
                                             const float* __restrict__ sd,
                                             float* __restrict__ JstP)
{
    const int j = blockIdx.x;
    const int c = blockIdx.y;
    const int tid = threadIdx.x;
    const int v0 = c * 862;
    const int v1 = (c == 7) ? V_ : v0 + 862;

    float acc[33];
#pragma unroll
    for (int q = 0; q < 33; q++) acc[q] = 0.f;

    for (int v = v0 + tid; v < v1; v += 256) {
        float jr = JR[(size_t)j * V_ + v];
        const float* tv = vtm + (size_t)v * 3;
        acc[0] += jr * tv[0];
        acc[1] += jr * tv[1];
        acc[2] += jr * tv[2];
#pragma unroll
        for (int k = 0; k < 10; k++) {
            const float* sp = sd + (size_t)k * V3_ + (size_t)v * 3;
            acc[3 + k*3 + 0] += jr * sp[0];
            acc[3 + k*3 + 1] += jr * sp[1];
            acc[3 + k*3 + 2] += jr * sp[2];
        }
    }
#pragma unroll
    for (int q = 0; q < 33; q++) {
        float s = acc[q];
#pragma unroll
        for (int off = 32; off > 0; off >>= 1) s += __shfl_xor(s, off);
        acc[q] = s;
    }
    __shared__ float red[4][33];
    const int wv = tid >> 6, ln = tid & 63;
    if (ln == 0) {
#pragma unroll
        for (int q = 0; q < 33; q++) red[wv][q] = acc[q];
    }
    __syncthreads();
    if (tid < 33)
        JstP[(c * 24 + j) * 33 + tid] =
            red[0][tid] + red[1][tid] + red[2][tid] + red[3][tid];
}

// ---------------------------------------------------------------------------
// K1: reduce JstP + rodrigues + kinematic chain.  64 thr/block, grid 4.
// ---------------------------------------------------------------------------
__global__ __launch_bounds__(64) void k_chain(const float* __restrict__ beta,
                                              const float* __restrict__ theta,
                                              const float* __restrict__ JstP,
                                              float* __restrict__ coefG,
                                              float* __restrict__ Aout)
{
    __shared__ float resL[24 * 12 * 64];
    __shared__ float JL[24 * 3 * 64];
    __shared__ float JstL[792];
    const int t = threadIdx.x;            // 0..63
    const int b = blockIdx.x * 64 + t;

    for (int i = t; i < 792; i += 64) {
        float s = 0.f;
#pragma unroll
        for (int c = 0; c < 8; c++) s += JstP[c * 792 + i];
        JstL[i] = s;
    }
    __syncthreads();

    float bet[10];
#pragma unroll
    for (int k = 0; k < 10; k++) bet[k] = beta[b * 10 + k];
#pragma unroll
    for (int k = 0; k < 10; k++) coefG[k * 256 + b] = bet[k];

#pragma unroll
    for (int j = 0; j < 24; j++) {
#pragma unroll
        for (int d = 0; d < 3; d++) {
            float s = JstL[j * 33 + d];
#pragma unroll
            for (int k = 0; k < 10; k++) s += bet[k] * JstL[j * 33 + 3 + k * 3 + d];
            JL[(j * 3 + d) * 64 + t] = s;
        }
    }

    const int par[24] = {0,0,0,0,1,2,3,4,5,6,7,8,9,9,9,12,13,14,16,17,18,19,20,21};

#pragma unroll
    for (int j = 0; j < 24; j++) {
        float t0 = theta[b * 72 + 3 * j + 0];
        float t1 = theta[b * 72 + 3 * j + 1];
        float t2 = theta[b * 72 + 3 * j + 2];
        float e0 = t0 + 1e-8f, e1 = t1 + 1e-8f, e2 = t2 + 1e-8f;
        float ang = sqrtf(e0 * e0 + e1 * e1 + e2 * e2);
        float inva = 1.0f / ang;
        float r0 = t0 * inva, r1 = t1 * inva, r2 = t2 * inva;
        float h = 0.5f * ang;
        float qw = cosf(h), sh = sinf(h);
        float qx = sh * r0, qy = sh * r1, qz = sh * r2;
        float qn = sqrtf(qw * qw + qx * qx + qy * qy + qz * qz);
        float inq = 1.0f / qn;
        qw *= inq; qx *= inq; qy *= inq; qz *= inq;
        float R[9];
        R[0] = 1.f - 2.f * (qy * qy + qz * qz);
        R[1] = 2.f * (qx * qy - qw * qz);
        R[2] = 2.f * (qx * qz + qw * qy);
        R[3] = 2.f * (qx * qy + qw * qz);
        R[4] = 1.f - 2.f * (qx * qx + qz * qz);
        R[5] = 2.f * (qy * qz - qw * qx);
        R[6] = 2.f * (qx * qz - qw * qy);
        R[7] = 2.f * (qy * qz + qw * qx);
        R[8] = 1.f - 2.f * (qx * qx + qy * qy);

        if (j == 0) {
#pragma unroll
            for (int m = 0; m < 3; m++) {
                resL[(0 * 12 + m * 4 + 0) * 64 + t] = R[m * 3 + 0];
                resL[(0 * 12 + m * 4 + 1) * 64 + t] = -R[m * 3 + 1];
                resL[(0 * 12 + m * 4 + 2) * 64 + t] = -R[m * 3 + 2];
                resL[(0 * 12 + m * 4 + 3) * 64 + t] = JL[(0 * 3 + m) * 64 + t];
            }
        } else {
#pragma unroll
            for (int e = 0; e < 9; e++)
                coefG[(10 + (j - 1) * 9 + e) * 256 + b] =
                    R[e] - ((e == 0 || e == 4 || e == 8) ? 1.f : 0.f);
            const int p = par[j];
            float tx = JL[(j * 3 + 0) * 64 + t] - JL[(p * 3 + 0) * 64 + t];
            float ty = JL[(j * 3 + 1) * 64 + t] - JL[(p * 3 + 1) * 64 + t];
            float tz = JL[(j * 3 + 2) * 64 + t] - JL[(p * 3 + 2) * 64 + t];
#pragma unroll
            for (int m = 0; m < 3; m++) {
                float pm0 = resL[(p * 12 + m * 4 + 0) * 64 + t];
                float pm1 = resL[(p * 12 + m * 4 + 1) * 64 + t];
                float pm2 = resL[(p * 12 + m * 4 + 2) * 64 + t];
                float pm3 = resL[(p * 12 + m * 4 + 3) * 64 + t];
                resL[(j * 12 + m * 4 + 0) * 64 + t] = pm0 * R[0] + pm1 * R[3] + pm2 * R[6];
                resL[(j * 12 + m * 4 + 1) * 64 + t] = pm0 * R[1] + pm1 * R[4] + pm2 * R[7];
                resL[(j * 12 + m * 4 + 2) * 64 + t] = pm0 * R[2] + pm1 * R[5] + pm2 * R[8];
                resL[(j * 12 + m * 4 + 3) * 64 + t] = pm0 * tx + pm1 * ty + pm2 * tz + pm3;
            }
        }
    }

#pragma unroll
    for (int j = 0; j < 24; j++) {
        float Jx = JL[(j * 3 + 0) * 64 + t];
        float Jy = JL[(j * 3 + 1) * 64 + t];
        float Jz = JL[(j * 3 + 2) * 64 + t];
#pragma unroll
        for (int m = 0; m < 3; m++) {
            float c0 = resL[(j * 12 + m * 4 + 0) * 64 + t];
            float c1 = resL[(j * 12 + m * 4 + 1) * 64 + t];
            float c2 = resL[(j * 12 + m * 4 + 2) * 64 + t];
            float c3 = resL[(j * 12 + m * 4 + 3) * 64 + t];
            float* ap = Aout + (size_t)(b * 24 + j) * 12 + m * 4;
            ap[0] = c0; ap[1] = c1; ap[2] = c2;
            ap[3] = c3 - (c0 * Jx + c1 * Jy + c2 * Jz);
        }
    }
}

// ---------------------------------------------------------------------------
// K2: v_posed GEMM with depth-8 register ring pipeline (16 loads in flight).
// Block = 32 batches x 128 cols; thread = 4b x 4c.
// ---------------------------------------------------------------------------
__global__ __launch_bounds__(256) void k_vposed(const float* __restrict__ cg,
                                                const float* __restrict__ vt,
                                                const float* __restrict__ sd,
                                                const float* __restrict__ pd,
                                                float* __restrict__ vp)
{
    __shared__ __align__(16) float coefT[NK_ * 32];
    const int tid = threadIdx.x;
    const int bblk = blockIdx.y * 32;
    for (int idx = tid; idx < NK_ * 32; idx += 256)
        coefT[idx] = cg[(idx >> 5) * 256 + bblk + (idx & 31)];
    __syncthreads();

    const int tx = tid & 31, ty = tid >> 5;
    int ibase = blockIdx.x * 128 + tx * 4;
    if (ibase > V3_ - 4) ibase = V3_ - 4;

    float acc[4][4];
#pragma unroll
    for (int i = 0; i < 4; i++)
#pragma unroll
        for (int q = 0; q < 4; q++) acc[i][q] = 0.f;

    float2 bufA[8], bufB[8];

#define K2_FMA(K, U)                                                          \
    {                                                                         \
        const float4 c4 = *(const float4*)(coefT + (K) * 32 + ty * 4);        \
        float2 cA = bufA[U], cB = bufB[U];                                    \
        acc[0][0] += c4.x * cA.x; acc[0][1] += c4.x * cA.y;                   \
        acc[0][2] += c4.x * cB.x; acc[0][3] += c4.x * cB.y;                   \
        acc[1][0] += c4.y * cA.x; acc[1][1] += c4.y * cA.y;                   \
        acc[1][2] += c4.y * cB.x; acc[1][3] += c4.y * cB.y;                   \
        acc[2][0] += c4.z * cA.x; acc[2][1] += c4.z * cA.y;                   \
        acc[2][2] += c4.z * cB.x; acc[2][3] += c4.z * cB.y;                   \
        acc[3][0] += c4.w * cA.x; acc[3][1] += c4.w * cA.y;                   \
        acc[3][2] += c4.w * cB.x; acc[3][3] += c4.w * cB.y;                   \
    }

    // prologue: rows 0..7 (all sd, since NB=10)
#pragma unroll
    for (int r = 0; r < 8; r++) {
        const float* p = sd + (size_t)r * V3_ + ibase;
        bufA[r] = *(const float2*)(p);
        bufB[r] = *(const float2*)(p + 2);
    }
    // pre-loop k=0..7: consume buf[k], prefetch row k+8 (8,9 from sd; 10..15 from pd)
#pragma unroll
    for (int k = 0; k < 8; k++) {
        K2_FMA(k, k)
        const int kn = k + 8;
        const float* p = (kn < 10) ? (sd + (size_t)kn * V3_ + ibase)
                                   : (pd + (size_t)(kn - 10) * V3_ + ibase);
        bufA[k] = *(const float2*)(p);
        bufB[k] = *(const float2*)(p + 2);
    }
    // main loop k=8..215 (26 x 8); prefetch row k+8 (always pd; clamp to 216)
    for (int kb = 8; kb < 216; kb += 8) {
#pragma unroll
        for (int u = 0; u < 8; u++) {
            const int k = kb + u;
            K2_FMA(k, u)
            int kn = k + 8;
            if (kn > 216) kn = 216;
            const float* p = pd + (size_t)(kn - 10) * V3_ + ibase;
            bufA[u] = *(const float2*)(p);
            bufB[u] = *(const float2*)(p + 2);
        }
    }
    // epilogue k=216
    K2_FMA(216, 0)
#undef K2_FMA

    float2 vA = *(const float2*)(vt + ibase);
    float2 vB = *(const float2*)(vt + ibase + 2);
#pragma unroll
    for (int i = 0; i < 4; i++) {
        int b = bblk + ty * 4 + i;
        float* o = vp + (size_t)b * V3_ + ibase;
        float2 o0 = {acc[i][0] + vA.x, acc[i][1] + vA.y};
        float2 o1 = {acc[i][2] + vB.x, acc[i][3] + vB.y};
        *(float2*)o = o0;
        *(float2*)(o + 2) = o1;
    }
}

// ---------------------------------------------------------------------------
// K3: skinning, in place in d_out.  weights batch-broadcast -> slice [0].
// ---------------------------------------------------------------------------
__global__ __launch_bounds__(256) void k_skin(const float* __restrict__ w0,
                                              const float* __restrict__ A,
                                              float* __restrict__ verts)
{
    __shared__ __align__(16) float AL[288];
    const int tid = threadIdx.x;
    const int b = blockIdx.y;
    for (int i = tid; i < 288; i += 256) AL[i] = A[(size_t)b * 288 + i];
    __syncthreads();

#pragma unroll
    for (int rep = 0; rep < 2; rep++) {
        int v = blockIdx.x * 512 + rep * 256 + tid;
        if (v >= V_) continue;
        float wr[24];
        const float4* wp = (const float4*)(w0 + (size_t)v * 24);
#pragma unroll
        for (int q = 0; q < 6; q++) {
            float4 f = wp[q];
            wr[q * 4 + 0] = f.x; wr[q * 4 + 1] = f.y;
            wr[q * 4 + 2] = f.z; wr[q * 4 + 3] = f.w;
        }
        float T[12];
#pragma unroll
        for (int e = 0; e < 12; e++) T[e] = 0.f;
#pragma unroll
        for (int j = 0; j < 24; j++) {
            const float4* a4 = (const float4*)(AL + j * 12);
            float4 a0 = a4[0], a1 = a4[1], a2 = a4[2];
            float wj = wr[j];
            T[0] += wj * a0.x; T[1] += wj * a0.y; T[2]  += wj * a0.z; T[3]  += wj * a0.w;
            T[4] += wj * a1.x; T[5] += wj * a1.y; T[6]  += wj * a1.z; T[7]  += wj * a1.w;
            T[8] += wj * a2.x; T[9] += wj * a2.y; T[10] += wj * a2.z; T[11] += wj * a2.w;
        }
        float* pv = verts + (size_t)b * V3_ + (size_t)v * 3;
        float p0 = pv[0], p1 = pv[1], p2 = pv[2];
        pv[0] = T[0] * p0 + T[1] * p1 + T[2]  * p2 + T[3];
        pv[1] = T[4] * p0 + T[5] * p1 + T[6]  * p2 + T[7];
        pv[2] = T[8] * p0 + T[9] * p1 + T[10] * p2 + T[11];
    }
}

// ---------------------------------------------------------------------------
// K4: joint regression partials over V/4 chunks.  grid (64, 6, 4).
// ---------------------------------------------------------------------------
__global__ __launch_bounds__(256) void k_joints(const float* __restrict__ jreg,
                                                const float* __restrict__ verts,
                                                float* __restrict__ jp)
{
    const int tid = threadIdx.x;
    const int b0 = blockIdx.x * 4;
    const int jr0 = blockIdx.y * 8;
    const int z = blockIdx.z;
    const int v0 = z * 1723;
    const int v1 = (z == 3) ? V_ : v0 + 1723;

    float acc[96];
#pragma unroll
    for (int c = 0; c < 96; c++) acc[c] = 0.f;

    for (int v = v0 + tid; v < v1; v += 256) {
        float jr[8];
#pragma unroll
        for (int q = 0; q < 8; q++) {
            int j = jr0 + q;
            jr[q] = (j < NJR_) ? jreg[(size_t)j * V_ + v] : 0.f;
        }
#pragma unroll
        for (int i = 0; i < 4; i++) {
            const float* pv = verts + (size_t)(b0 + i) * V3_ + (size_t)v * 3;
            float p0 = pv[0], p1 = pv[1], p2 = pv[2];
#pragma unroll
            for (int q = 0; q < 8; q++) {
                acc[q * 12 + i * 3 + 0] += jr[q] * p0;
                acc[q * 12 + i * 3 + 1] += jr[q] * p1;
                acc[q * 12 + i * 3 + 2] += jr[q] * p2;
            }
        }
    }
#pragma unroll
    for (int c = 0; c < 96; c++) {
        float s = acc[c];
#pragma unroll
        for (int off = 32; off > 0; off >>= 1) s += __shfl_xor(s, off);
        acc[c] = s;
    }
    __shared__ float red[4][96];
    const int wv = tid >> 6, ln = tid & 63;
    if (ln == 0) {
#pragma unroll
        for (int c = 0; c < 96; c++) red[wv][c] = acc[c];
    }
    __syncthreads();
    if (tid < 96) {
        float s = red[0][tid] + red[1][tid] + red[2][tid] + red[3][tid];
        int q = tid / 12, rem = tid % 12, i2 = rem / 3, d = rem % 3;
        int j = jr0 + q;
        if (j < NJR_)
            jp[(size_t)z * JOUT_ + (b0 + i2) * NJ3_ + j * 3 + d] = s;
    }
}

// K5: sum the 4 partials into joints output
__global__ __launch_bounds__(256) void k_jfinal(const float* __restrict__ jp,
                                                float* __restrict__ joints)
{
    int i = blockIdx.x * 256 + threadIdx.x;
    if (i < JOUT_)
        joints[i] = jp[i] + jp[JOUT_ + i] + jp[2 * JOUT_ + i] + jp[3 * JOUT_ + i];
}

extern "C" void kernel_launch(void* const* d_in, const int* in_sizes, int n_in,
                              void* d_out, int out_size, void* d_ws, size_t ws_size,
                              hipStream_t stream)
{
    const float* beta  = (const float*)d_in[0];
    const float* theta = (const float*)d_in[1];
    const float* vtm   = (const float*)d_in[2];
    const float* sd    = (const float*)d_in[3];
    const float* pd    = (const float*)d_in[4];
    const float* JR    = (const float*)d_in[5];
    const float* jreg  = (const float*)d_in[6];
    const float* wts   = (const float*)d_in[7];  // batch-broadcast: slice [0]

    float* out = (float*)d_out;
    float* ws  = (float*)d_ws;
    float* JstP = ws + JSTP_OFF;
    float* cg   = ws + CG_OFF;
    float* A    = ws + A_OFF;
    float* jp   = ws + JP_OFF;
    float* verts  = out;
    float* joints = out + (size_t)B_ * V3_;

    hipLaunchKernelGGL(k_jst,    dim3(24, 8),      dim3(256), 0, stream, JR, vtm, sd, JstP);
    hipLaunchKernelGGL(k_chain,  dim3(4),          dim3(64),  0, stream, beta, theta, JstP, cg, A);
    hipLaunchKernelGGL(k_vposed, dim3(162, 8),     dim3(256), 0, stream, cg, vtm, sd, pd, verts);
    hipLaunchKernelGGL(k_skin,   dim3(14, 256),    dim3(256), 0, stream, wts, A, verts);
    hipLaunchKernelGGL(k_joints, dim3(64, 6, 4),   dim3(256), 0, stream, jreg, verts, jp);
    hipLaunchKernelGGL(k_jfinal, dim3(129),        dim3(256), 0, stream, jp, joints);
}

// Round 4
// 399.060 us; speedup vs baseline: 1.4553x; 1.4553x over previous
//
#include <hip/hip_runtime.h>
#include <math.h>

#define B_   256
#define V_   6890
#define NJ_  24
#define NB_  10
#define NP_  207
#define NJR_ 43
#define V3_  20670   // V*3
#define NK_  217     // NB + NP
#define NJ3_ 129     // NJR*3
#define JOUT_ 33024  // B*NJR*3

// ws layout (floats)
#define JSTP_OFF 0        // 8 * 792 partial Jst
#define CG_OFF   8192     // coefG: 217*256
#define A_OFF    65536    // 256*24*12 = 73728
#define JP_OFF   139264   // joint partials: 4 * 33024 = 132096

// ---------------------------------------------------------------------------
// K0: partial Jst over V-chunks.  grid (24 joints, 8 chunks).
// ---------------------------------------------------------------------------
__global__ __launch_bounds__(256) void k_jst(const float* __restrict__ JR,
                                             const float* __restrict__ vtm,
                                             const float* __restrict__ sd,
                                             float* __restrict__ JstP)
{
    const int j = blockIdx.x;
    const int c = blockIdx.y;
    const int tid = threadIdx.x;
    const int v0 = c * 862;
    const int v1 = (c == 7) ? V_ : v0 + 862;

    float acc[33];
#pragma unroll
    for (int q = 0; q < 33; q++) acc[q] = 0.f;

    for (int v = v0 + tid; v < v1; v += 256) {
        float jr = JR[(size_t)j * V_ + v];
        const float* tv = vtm + (size_t)v * 3;
        acc[0] += jr * tv[0];
        acc[1] += jr * tv[1];
        acc[2] += jr * tv[2];
#pragma unroll
        for (int k = 0; k < 10; k++) {
            const float* sp = sd + (size_t)k * V3_ + (size_t)v * 3;
            acc[3 + k*3 + 0] += jr * sp[0];
            acc[3 + k*3 + 1] += jr * sp[1];
            acc[3 + k*3 + 2] += jr * sp[2];
        }
    }
#pragma unroll
    for (int q = 0; q < 33; q++) {
        float s = acc[q];
#pragma unroll
        for (int off = 32; off > 0; off >>= 1) s += __shfl_xor(s, off);
        acc[q] = s;
    }
    __shared__ float red[4][33];
    const int wv = tid >> 6, ln = tid & 63;
    if (ln == 0) {
#pragma unroll
        for (int q = 0; q < 33; q++) red[wv][q] = acc[q];
    }
    __syncthreads();
    if (tid < 33)
        JstP[(c * 24 + j) * 33 + tid] =
            red[0][tid] + red[1][tid] + red[2][tid] + red[3][tid];
}

// ---------------------------------------------------------------------------
// K1: reduce JstP + rodrigues + kinematic chain.  64 thr/block, grid 4.
// ---------------------------------------------------------------------------
__global__ __launch_bounds__(64) void k_chain(const float* __restrict__ beta,
                                              const float* __restrict__ theta,
                                              const float* __restrict__ JstP,
                                              float* __restrict__ coefG,
                                              float* __restrict__ Aout)
{
    __shared__ float resL[24 * 12 * 64];
    __shared__ float JL[24 * 3 * 64];
    __shared__ float JstL[792];
    const int t = threadIdx.x;
    const int b = blockIdx.x * 64 + t;

    for (int i = t; i < 792; i += 64) {
        float s = 0.f;
#pragma unroll
        for (int c = 0; c < 8; c++) s += JstP[c * 792 + i];
        JstL[i] = s;
    }
    __syncthreads();

    float bet[10];
#pragma unroll
    for (int k = 0; k < 10; k++) bet[k] = beta[b * 10 + k];
#pragma unroll
    for (int k = 0; k < 10; k++) coefG[k * 256 + b] = bet[k];

#pragma unroll
    for (int j = 0; j < 24; j++) {
#pragma unroll
        for (int d = 0; d < 3; d++) {
            float s = JstL[j * 33 + d];
#pragma unroll
            for (int k = 0; k < 10; k++) s += bet[k] * JstL[j * 33 + 3 + k * 3 + d];
            JL[(j * 3 + d) * 64 + t] = s;
        }
    }

    const int par[24] = {0,0,0,0,1,2,3,4,5,6,7,8,9,9,9,12,13,14,16,17,18,19,20,21};

#pragma unroll
    for (int j = 0; j < 24; j++) {
        float t0 = theta[b * 72 + 3 * j + 0];
        float t1 = theta[b * 72 + 3 * j + 1];
        float t2 = theta[b * 72 + 3 * j + 2];
        float e0 = t0 + 1e-8f, e1 = t1 + 1e-8f, e2 = t2 + 1e-8f;
        float ang = sqrtf(e0 * e0 + e1 * e1 + e2 * e2);
        float inva = 1.0f / ang;
        float r0 = t0 * inva, r1 = t1 * inva, r2 = t2 * inva;
        float h = 0.5f * ang;
        float qw = cosf(h), sh = sinf(h);
        float qx = sh * r0, qy = sh * r1, qz = sh * r2;
        float qn = sqrtf(qw * qw + qx * qx + qy * qy + qz * qz);
        float inq = 1.0f / qn;
        qw *= inq; qx *= inq; qy *= inq; qz *= inq;
        float R[9];
        R[0] = 1.f - 2.f * (qy * qy + qz * qz);
        R[1] = 2.f * (qx * qy - qw * qz);
        R[2] = 2.f * (qx * qz + qw * qy);
        R[3] = 2.f * (qx * qy + qw * qz);
        R[4] = 1.f - 2.f * (qx * qx + qz * qz);
        R[5] = 2.f * (qy * qz - qw * qx);
        R[6] = 2.f * (qx * qz - qw * qy);
        R[7] = 2.f * (qy * qz + qw * qx);
        R[8] = 1.f - 2.f * (qx * qx + qy * qy);

        if (j == 0) {
#pragma unroll
            for (int m = 0; m < 3; m++) {
                resL[(0 * 12 + m * 4 + 0) * 64 + t] = R[m * 3 + 0];
                resL[(0 * 12 + m * 4 + 1) * 64 + t] = -R[m * 3 + 1];
                resL[(0 * 12 + m * 4 + 2) * 64 + t] = -R[m * 3 + 2];
                resL[(0 * 12 + m * 4 + 3) * 64 + t] = JL[(0 * 3 + m) * 64 + t];
            }
        } else {
#pragma unroll
            for (int e = 0; e < 9; e++)
                coefG[(10 + (j - 1) * 9 + e) * 256 + b] =
                    R[e] - ((e == 0 || e == 4 || e == 8) ? 1.f : 0.f);
            const int p = par[j];
            float tx = JL[(j * 3 + 0) * 64 + t] - JL[(p * 3 + 0) * 64 + t];
            float ty = JL[(j * 3 + 1) * 64 + t] - JL[(p * 3 + 1) * 64 + t];
            float tz = JL[(j * 3 + 2) * 64 + t] - JL[(p * 3 + 2) * 64 + t];
#pragma unroll
            for (int m = 0; m < 3; m++) {
                float pm0 = resL[(p * 12 + m * 4 + 0) * 64 + t];
                float pm1 = resL[(p * 12 + m * 4 + 1) * 64 + t];
                float pm2 = resL[(p * 12 + m * 4 + 2) * 64 + t];
                float pm3 = resL[(p * 12 + m * 4 + 3) * 64 + t];
                resL[(j * 12 + m * 4 + 0) * 64 + t] = pm0 * R[0] + pm1 * R[3] + pm2 * R[6];
                resL[(j * 12 + m * 4 + 1) * 64 + t] = pm0 * R[1] + pm1 * R[4] + pm2 * R[7];
                resL[(j * 12 + m * 4 + 2) * 64 + t] = pm0 * R[2] + pm1 * R[5] + pm2 * R[8];
                resL[(j * 12 + m * 4 + 3) * 64 + t] = pm0 * tx + pm1 * ty + pm2 * tz + pm3;
            }
        }
    }

#pragma unroll
    for (int j = 0; j < 24; j++) {
        float Jx = JL[(j * 3 + 0) * 64 + t];
        float Jy = JL[(j * 3 + 1) * 64 + t];
        float Jz = JL[(j * 3 + 2) * 64 + t];
#pragma unroll
        for (int m = 0; m < 3; m++) {
            float c0 = resL[(j * 12 + m * 4 + 0) * 64 + t];
            float c1 = resL[(j * 12 + m * 4 + 1) * 64 + t];
            float c2 = resL[(j * 12 + m * 4 + 2) * 64 + t];
            float c3 = resL[(j * 12 + m * 4 + 3) * 64 + t];
            float* ap = Aout + (size_t)(b * 24 + j) * 12 + m * 4;
            ap[0] = c0; ap[1] = c1; ap[2] = c2;
            ap[3] = c3 - (c0 * Jx + c1 * Jy + c2 * Jz);
        }
    }
}

// ---------------------------------------------------------------------------
// K2: v_posed GEMM, batch-stationary.  Grid = 646 strips of 32 cols; each
// block covers ALL 256 batches -> sd/pd read exactly once device-wide.
// Thread = 4 batches x 8 cols.  Dir tile staged 64 rows at a time in LDS;
// row values wave-broadcast via ds_read_b128 (lanes share address).
// ---------------------------------------------------------------------------
__global__ __launch_bounds__(256) void k_vposed(const float* __restrict__ cg,
                                                const float* __restrict__ vt,
                                                const float* __restrict__ sd,
                                                const float* __restrict__ pd,
                                                float* __restrict__ vp)
{
    __shared__ __align__(16) float tile[64 * 32];
    const int tid  = threadIdx.x;
    const int cbase = blockIdx.x * 32;
    const bool tail = (cbase + 32 > V3_);     // only last block (cols 20640..20669)
    const int b0  = (tid & 63) * 4;           // 4 consecutive batches
    const int cg8 = tid >> 6;                 // col group (8 cols), wave-uniform

    float acc[4][8];
#pragma unroll
    for (int i = 0; i < 4; i++)
#pragma unroll
        for (int j = 0; j < 8; j++) acc[i][j] = 0.f;

    for (int kb = 0; kb < NK_; kb += 64) {
        const int rows = (NK_ - kb < 64) ? (NK_ - kb) : 64;
        __syncthreads();   // previous chunk's reads done before overwrite
        // stage rows [kb, kb+rows) x 32 cols; float2 (V3_ odd*2 -> 8B align only)
#pragma unroll
        for (int i = 0; i < 4; i++) {
            int s = tid + 256 * i;            // 0..1023 slots of 2 floats
            int r = s >> 4, c2 = (s & 15) * 2;
            if (r < rows) {
                int gr = kb + r;
                const float* src = ((gr < NB_) ? (sd + (size_t)gr * V3_)
                                               : (pd + (size_t)(gr - NB_) * V3_))
                                   + cbase + c2;
                float2 vv;
                if (!tail) {
                    vv = *(const float2*)src;
                } else {
                    vv.x = (cbase + c2     < V3_) ? src[0] : 0.f;
                    vv.y = (cbase + c2 + 1 < V3_) ? src[1] : 0.f;
                }
                *(float2*)(tile + r * 32 + c2) = vv;
            }
        }
        __syncthreads();
        // compute
#pragma unroll 8
        for (int u = 0; u < rows; u++) {
            const float4 c4 = *(const float4*)(cg + (size_t)(kb + u) * 256 + b0);
            const float* rv = tile + u * 32 + cg8 * 8;
            const float4 vA = *(const float4*)(rv);
            const float4 vB = *(const float4*)(rv + 4);
            float ci[4] = {c4.x, c4.y, c4.z, c4.w};
            float vj[8] = {vA.x, vA.y, vA.z, vA.w, vB.x, vB.y, vB.z, vB.w};
#pragma unroll
            for (int i = 0; i < 4; i++)
#pragma unroll
                for (int j = 0; j < 8; j++) acc[i][j] += ci[i] * vj[j];
        }
    }

    // epilogue: add v_template, store
    const int col0 = cbase + cg8 * 8;
    if (!tail) {
        const float4 tA = *(const float4*)(vt + col0);
        const float4 tB = *(const float4*)(vt + col0 + 4);
        float tv[8] = {tA.x, tA.y, tA.z, tA.w, tB.x, tB.y, tB.z, tB.w};
#pragma unroll
        for (int i = 0; i < 4; i++) {
            float* o = vp + (size_t)(b0 + i) * V3_ + col0;
#pragma unroll
            for (int q = 0; q < 4; q++) {
                float2 st = {acc[i][2*q] + tv[2*q], acc[i][2*q+1] + tv[2*q+1]};
                *(float2*)(o + 2*q) = st;   // 8B-aligned always (odd b rows)
            }
        }
    } else {
        float tv[8];
#pragma unroll
        for (int j = 0; j < 8; j++) tv[j] = (col0 + j < V3_) ? vt[col0 + j] : 0.f;
#pragma unroll
        for (int i = 0; i < 4; i++) {
            float* o = vp + (size_t)(b0 + i) * V3_ + col0;
#pragma unroll
            for (int j = 0; j < 8; j++)
                if (col0 + j < V3_) o[j] = acc[i][j] + tv[j];
        }
    }
}

// ---------------------------------------------------------------------------
// K3: skinning, in place in d_out.  weights batch-broadcast -> slice [0].
// ---------------------------------------------------------------------------
__global__ __launch_bounds__(256) void k_skin(const float* __restrict__ w0,
                                              const float* __restrict__ A,
                                              float* __restrict__ verts)
{
    __shared__ __align__(16) float AL[288];
    const int tid = threadIdx.x;
    const int b = blockIdx.y;
    for (int i = tid; i < 288; i += 256) AL[i] = A[(size_t)b * 288 + i];
    __syncthreads();

#pragma unroll
    for (int rep = 0; rep < 2; rep++) {
        int v = blockIdx.x * 512 + rep * 256 + tid;
        if (v >= V_) continue;
        float wr[24];
        const float4* wp = (const float4*)(w0 + (size_t)v * 24);
#pragma unroll
        for (int q = 0; q < 6; q++) {
            float4 f = wp[q];
            wr[q * 4 + 0] = f.x; wr[q * 4 + 1] = f.y;
            wr[q * 4 + 2] = f.z; wr[q * 4 + 3] = f.w;
        }
        float T[12];
#pragma unroll
        for (int e = 0; e < 12; e++) T[e] = 0.f;
#pragma unroll
        for (int j = 0; j < 24; j++) {
            const float4* a4 = (const float4*)(AL + j * 12);
            float4 a0 = a4[0], a1 = a4[1], a2 = a4[2];
            float wj = wr[j];
            T[0] += wj * a0.x; T[1] += wj * a0.y; T[2]  += wj * a0.z; T[3]  += wj * a0.w;
            T[4] += wj * a1.x; T[5] += wj * a1.y; T[6]  += wj * a1.z; T[7]  += wj * a1.w;
            T[8] += wj * a2.x; T[9] += wj * a2.y; T[10] += wj * a2.z; T[11] += wj * a2.w;
        }
        float* pv = verts + (size_t)b * V3_ + (size_t)v * 3;
        float p0 = pv[0], p1 = pv[1], p2 = pv[2];
        pv[0] = T[0] * p0 + T[1] * p1 + T[2]  * p2 + T[3];
        pv[1] = T[4] * p0 + T[5] * p1 + T[6]  * p2 + T[7];
        pv[2] = T[8] * p0 + T[9] * p1 + T[10] * p2 + T[11];
    }
}

// ---------------------------------------------------------------------------
// K4: joint regression partials over V/4 chunks.  grid (64, 6, 4).
// ---------------------------------------------------------------------------
__global__ __launch_bounds__(256) void k_joints(const float* __restrict__ jreg,
                                                const float* __restrict__ verts,
                                                float* __restrict__ jp)
{
    const int tid = threadIdx.x;
    const int b0 = blockIdx.x * 4;
    const int jr0 = blockIdx.y * 8;
    const int z = blockIdx.z;
    const int v0 = z * 1723;
    const int v1 = (z == 3) ? V_ : v0 + 1723;

    float acc[96];
#pragma unroll
    for (int c = 0; c < 96; c++) acc[c] = 0.f;

    for (int v = v0 + tid; v < v1; v += 256) {
        float jr[8];
#pragma unroll
        for (int q = 0; q < 8; q++) {
            int j = jr0 + q;
            jr[q] = (j < NJR_) ? jreg[(size_t)j * V_ + v] : 0.f;
        }
#pragma unroll
        for (int i = 0; i < 4; i++) {
            const float* pv = verts + (size_t)(b0 + i) * V3_ + (size_t)v * 3;
            float p0 = pv[0], p1 = pv[1], p2 = pv[2];
#pragma unroll
            for (int q = 0; q < 8; q++) {
                acc[q * 12 + i * 3 + 0] += jr[q] * p0;
                acc[q * 12 + i * 3 + 1] += jr[q] * p1;
                acc[q * 12 + i * 3 + 2] += jr[q] * p2;
            }
        }
    }
#pragma unroll
    for (int c = 0; c < 96; c++) {
        float s = acc[c];
#pragma unroll
        for (int off = 32; off > 0; off >>= 1) s += __shfl_xor(s, off);
        acc[c] = s;
    }
    __shared__ float red[4][96];
    const int wv = tid >> 6, ln = tid & 63;
    if (ln == 0) {
#pragma unroll
        for (int c = 0; c < 96; c++) red[wv][c] = acc[c];
    }
    __syncthreads();
    if (tid < 96) {
        float s = red[0][tid] + red[1][tid] + red[2][tid] + red[3][tid];
        int q = tid / 12, rem = tid % 12, i2 = rem / 3, d = rem % 3;
        int j = jr0 + q;
        if (j < NJR_)
            jp[(size_t)z * JOUT_ + (b0 + i2) * NJ3_ + j * 3 + d] = s;
    }
}

// K5: sum the 4 partials into joints output
__global__ __launch_bounds__(256) void k_jfinal(const float* __restrict__ jp,
                                                float* __restrict__ joints)
{
    int i = blockIdx.x * 256 + threadIdx.x;
    if (i < JOUT_)
        joints[i] = jp[i] + jp[JOUT_ + i] + jp[2 * JOUT_ + i] + jp[3 * JOUT_ + i];
}

extern "C" void kernel_launch(void* const* d_in, const int* in_sizes, int n_in,
                              void* d_out, int out_size, void* d_ws, size_t ws_size,
                              hipStream_t stream)
{
    const float* beta  = (const float*)d_in[0];
    const float* theta = (const float*)d_in[1];
    const float* vtm   = (const float*)d_in[2];
    const float* sd    = (const float*)d_in[3];
    const float* pd    = (const float*)d_in[4];
    const float* JR    = (const float*)d_in[5];
    const float* jreg  = (const float*)d_in[6];
    const float* wts   = (const float*)d_in[7];  // batch-broadcast: slice [0]

    float* out = (float*)d_out;
    float* ws  = (float*)d_ws;
    float* JstP = ws + JSTP_OFF;
    float* cg   = ws + CG_OFF;
    float* A    = ws + A_OFF;
    float* jp   = ws + JP_OFF;
    float* verts  = out;
    float* joints = out + (size_t)B_ * V3_;

    hipLaunchKernelGGL(k_jst,    dim3(24, 8),    dim3(256), 0, stream, JR, vtm, sd, JstP);
    hipLaunchKernelGGL(k_chain,  dim3(4),        dim3(64),  0, stream, beta, theta, JstP, cg, A);
    hipLaunchKernelGGL(k_vposed, dim3(646),      dim3(256), 0, stream, cg, vtm, sd, pd, verts);
    hipLaunchKernelGGL(k_skin,   dim3(14, 256),  dim3(256), 0, stream, wts, A, verts);
    hipLaunchKernelGGL(k_joints, dim3(64, 6, 4), dim3(256), 0, stream, jreg, verts, jp);
    hipLaunchKernelGGL(k_jfinal, dim3(129),      dim3(256), 0, stream, jp, joints);
}